// Round 4
// baseline (17.245 us; speedup 1.0000x reference)
//
#include <hip/hip_runtime.h>
#include <math.h>

// Problem constants (fixed by setup_inputs / module constants)
#define BS   4
#define GMAX 500
#define HW   65536           // 256*256
#define K_OFF 120            // 8*(1+2+3+4+5)
#define K_PAD 128            // padded to power of 2 (8 sentinels)
#define FLAG_OFF (BS * HW * 2)
#define DIS_THR 20.0f        // STRIDE*RADIUS
#define OFF_MAX 7241         // max |round(256*(dx+dy))| over the rings
#define TILE_SPAN 7967       // 31*256 + 31 (flat span of a 32x32 tile)

struct OffsetsArg { int v[K_PAD]; };

// ---------------------------------------------------------------------------
// One block = one 32x32 pixel tile of one image. 1024 threads, 1 px/thread.
// grid (8,8,BS) = 256 blocks -> 1 block/CU, no tail.
//   phase 1 (loop-free): each thread tests one GT point; wave-aggregated
//            append (ballot + 1 atomic/wave) into two LDS candidate lists:
//            (a) disk: coord box overlap +-22; (b) scatter: base flat index
//            within [nmin-OFF_MAX, nmin+TILE_SPAN+OFF_MAX].
//   phase 2: per-pixel disk test over list (exact R1-validated rounding).
//   phase 3: scnt*128 grid-stride pass, division-free (s=p>>7, k=p&127),
//            marks into 1024-entry LDS tile mask (idempotent writes).
//   phase 4: store pixels (float2) + flag = mark ? 1 : (covered ? 0 : -1).
// ---------------------------------------------------------------------------
__global__ __launch_bounds__(1024) void fused_kernel(
    const float* __restrict__ gt_points,   // (BS, GMAX, 2)
    const int*   __restrict__ gt_nums,     // (BS,)
    OffsetsArg offs,                       // 120 ring offsets + 8 sentinels
    float*       __restrict__ out)         // [BS*HW*2 pixels | BS*HW flag]
{
    const int b    = blockIdx.z;
    const int tx0  = blockIdx.x << 5;           // tile origin px
    const int ty0  = blockIdx.y << 5;           // tile origin py
    const int nmin = (tx0 << 8) + ty0;          // smallest flat index in tile

    __shared__ float4 sgp[GMAX];                // (gx, gy, g2, -) disk list
    __shared__ int    sbase[GMAX];              // scatter candidate bases
    __shared__ int    offl[K_PAD];
    __shared__ unsigned char smark[1024];
    __shared__ int    dcnt_, scnt_;

    const int tid  = threadIdx.x;
    const int lane = tid & 63;
    if (tid == 0) { dcnt_ = 0; scnt_ = 0; }
    smark[tid] = 0;
    if (tid < K_PAD) offl[tid] = offs.v[tid];

    // ---- phase 1: candidate build (one point per thread, no loop) ----
    const int num = gt_nums[b];
    bool dc = false, sc = false;
    float gx = 0.f, gy = 0.f, g2 = 0.f;
    int base = 0;
    if (tid < num) {
        const float2 gp = ((const float2*)gt_points)[b * GMAX + tid];
        gx = gp.x; gy = gp.y;
        dc = (gx >= (float)(tx0 - 22)) & (gx <= (float)(tx0 + 31 + 22)) &
             (gy >= (float)(ty0 - 22)) & (gy <= (float)(ty0 + 31 + 22));
        // validated base formula: x*256, y*256 exact, one rounded add, rint
        base = (int)rintf(__fadd_rn(__fmul_rn(gx, 256.0f),
                                    __fmul_rn(gy, 256.0f)));
        sc = (base >= nmin - OFF_MAX) & (base <= nmin + TILE_SPAN + OFF_MAX);
        g2 = __fadd_rn(__fmul_rn(gx, gx), __fmul_rn(gy, gy));
    }
    // wave-aggregated appends (1 atomic per wave per list)
    {
        const unsigned long long m = __ballot(dc);
        if (m) {
            const int ldr = __builtin_ctzll(m);
            int pos0 = 0;
            if (lane == ldr) pos0 = atomicAdd(&dcnt_, __popcll(m));
            pos0 = __shfl(pos0, ldr);
            if (dc)
                sgp[pos0 + __popcll(m & ((1ull << lane) - 1))] =
                    make_float4(gx, gy, g2, 0.0f);
        }
    }
    {
        const unsigned long long m = __ballot(sc);
        if (m) {
            const int ldr = __builtin_ctzll(m);
            int pos0 = 0;
            if (lane == ldr) pos0 = atomicAdd(&scnt_, __popcll(m));
            pos0 = __shfl(pos0, ldr);
            if (sc)
                sbase[pos0 + __popcll(m & ((1ull << lane) - 1))] = base;
        }
    }
    __syncthreads();

    // ---- phase 2: per-pixel disk coverage (exact rounded formula) ----
    const int pxi = tx0 + (tid >> 5), pyi = ty0 + (tid & 31);
    const float px = (float)pxi, py = (float)pyi;
    const float p2 = px * px + py * py;          // exact (ints < 2^24)

    bool found = false;
    const int dcnt = dcnt_;
    for (int i = 0; i < dcnt; ++i) {
        const float4 gp = sgp[i];                // broadcast ds_read_b128
        const float cross = __fadd_rn(__fmul_rn(px, gp.x),
                                      __fmul_rn(py, gp.y));
        const float d2 = __fsub_rn(__fadd_rn(p2, gp.z),
                                   __fmul_rn(2.0f, cross));
        found |= (sqrtf(fmaxf(d2, 0.0f)) <= DIS_THR);
    }

    // ---- phase 3: scatter marks, division-free ----
    const int total = scnt_ * K_PAD;
    for (int p = tid; p < total; p += 1024) {
        const int s = p >> 7;
        const int k = p & (K_PAD - 1);
        const unsigned local = (unsigned)(sbase[s] + offl[k] - nmin);
        // in-tile iff row-rel <= 31 (implied by local<=TILE_SPAN) & col-rel < 32
        if (local <= (unsigned)TILE_SPAN && (local & 255u) < 32u)
            smark[((local >> 8) << 5) | (local & 31u)] = 1;
    }
    __syncthreads();

    // ---- phase 4: stores; priority scatter(+1) > covered(0) > negative(-1) ----
    const int n = (pxi << 8) | pyi;
    ((float2*)out)[b * HW + n] = make_float2(px, py);
    out[FLAG_OFF + b * HW + n] = smark[tid] ? 1.0f : (found ? 0.0f : -1.0f);
}

extern "C" void kernel_launch(void* const* d_in, const int* in_sizes, int n_in,
                              void* d_out, int out_size, void* d_ws, size_t ws_size,
                              hipStream_t stream) {
    // inputs: [0] images (unused), [1] gt_points, [2] gt_nums
    const float* gt_points = (const float*)d_in[1];
    const int*   gt_nums   = (const int*)d_in[2];
    float* out = (float*)d_out;

    // Ring offsets: host double trig (libm, matches numpy), half-even rint.
    OffsetsArg offs;
    {
        int k = 0;
        for (int i = 0; i < 5; ++i) {
            const int    nn = 8 * (i + 1);
            const double r  = 4.0 * (i + 1);
            for (int j = 0; j < nn; ++j) {
                const double ang = (double)j / (double)nn * 2.0 * M_PI;
                offs.v[k++] = (int)rint(r * sin(ang) * 256.0 +
                                        r * cos(ang) * 256.0);
            }
        }
        for (; k < K_PAD; ++k) offs.v[k] = -0x40000000;  // sentinel: never in-tile
    }

    fused_kernel<<<dim3(8, 8, BS), 1024, 0, stream>>>(gt_points, gt_nums, offs, out);
}

// Round 5
// 12.652 us; speedup vs baseline: 1.3630x; 1.3630x over previous
//
#include <hip/hip_runtime.h>
#include <math.h>

// Problem constants (fixed by setup_inputs / module constants)
#define BS   4
#define GMAX 500
#define HW   65536           // 256*256
#define K_OFF 120            // 8*(1+2+3+4+5) raw ring offsets
#define K_PAD 64             // deduped (~61 unique) + sentinels, power of 2
#define FLAG_OFF (BS * HW * 2)
#define DIS_THR 20.0f        // STRIDE*RADIUS
#define OFF_MAX 7241         // max |round(256*(dx+dy))| over the rings
#define TILE_SPAN 3855       // 15*256 + 15 (flat span of a 16x16 tile)

struct OffsetsArg { int v[K_PAD]; };

// ---------------------------------------------------------------------------
// One block = one 16x16 pixel tile of one image. 256 threads, 1 px/thread.
// grid (16,16,BS) = 1024 blocks -> 4 blocks/CU (inter-block latency hiding).
//   phase 1: 2-iter scan of GT points; wave-aggregated append (ballot +
//            1 atomic/wave/list) into LDS candidate lists:
//            (a) disk: coord box overlap +-22 -> (gx,gy,g2,-) float4
//            (b) scatter: base flat index within +-OFF_MAX of tile span
//   phase 2: per-pixel disk test over list (exact R1-validated rounding,
//            sqrtf kept: '<=' at the 1-ulp boundary must match np).
//   phase 3: scnt*64 grid-stride, division-free (s=p>>6, k=p&63), marks
//            into 256-entry LDS tile mask (idempotent constant writes).
//   phase 4: store pixels (float2) + flag = mark ? 1 : (covered ? 0 : -1).
// ---------------------------------------------------------------------------
__global__ __launch_bounds__(256) void fused_kernel(
    const float* __restrict__ gt_points,   // (BS, GMAX, 2)
    const int*   __restrict__ gt_nums,     // (BS,)
    OffsetsArg offs,                       // deduped ring offsets + sentinels
    float*       __restrict__ out)         // [BS*HW*2 pixels | BS*HW flag]
{
    const int b    = blockIdx.z;
    const int tx0  = blockIdx.x << 4;           // tile origin px
    const int ty0  = blockIdx.y << 4;           // tile origin py
    const int nmin = (tx0 << 8) + ty0;          // smallest flat index in tile

    __shared__ float4 sgp[GMAX];                // (gx, gy, g2, -) disk list
    __shared__ int    sbase[GMAX];              // scatter candidate bases
    __shared__ int    offl[K_PAD];
    __shared__ unsigned char smark[256];
    __shared__ int    dcnt_, scnt_;

    const int tid  = threadIdx.x;
    const int lane = tid & 63;
    if (tid == 0) { dcnt_ = 0; scnt_ = 0; }
    smark[tid] = 0;
    if (tid < K_PAD) offl[tid] = offs.v[tid];
    __syncthreads();                             // counters zeroed before atomics!

    // ---- phase 1: candidate build, wave-aggregated appends ----
    const int num = gt_nums[b];
    const float xlo = (float)(tx0 - 22), xhi = (float)(tx0 + 15 + 22);
    const float ylo = (float)(ty0 - 22), yhi = (float)(ty0 + 15 + 22);
    const int   blo = nmin - OFF_MAX,    bhi = nmin + TILE_SPAN + OFF_MAX;

    for (int g = tid; g < num; g += 256) {
        const float2 gp = ((const float2*)gt_points)[b * GMAX + g];
        const float gx = gp.x, gy = gp.y;
        const bool dc = (gx >= xlo) & (gx <= xhi) & (gy >= ylo) & (gy <= yhi);
        // validated base formula: x*256, y*256 exact, one rounded add, rint
        const int base = (int)rintf(__fadd_rn(__fmul_rn(gx, 256.0f),
                                              __fmul_rn(gy, 256.0f)));
        const bool sc = (base >= blo) & (base <= bhi);

        {
            const unsigned long long m = __ballot(dc);
            if (m) {
                const int ldr = __builtin_ctzll(m);
                int pos0 = 0;
                if (lane == ldr) pos0 = atomicAdd(&dcnt_, __popcll(m));
                pos0 = __shfl(pos0, ldr);
                if (dc) {
                    const float g2 = __fadd_rn(__fmul_rn(gx, gx),
                                               __fmul_rn(gy, gy));
                    sgp[pos0 + __popcll(m & ((1ull << lane) - 1))] =
                        make_float4(gx, gy, g2, 0.0f);
                }
            }
        }
        {
            const unsigned long long m = __ballot(sc);
            if (m) {
                const int ldr = __builtin_ctzll(m);
                int pos0 = 0;
                if (lane == ldr) pos0 = atomicAdd(&scnt_, __popcll(m));
                pos0 = __shfl(pos0, ldr);
                if (sc)
                    sbase[pos0 + __popcll(m & ((1ull << lane) - 1))] = base;
            }
        }
    }
    __syncthreads();

    // ---- phase 2: per-pixel disk coverage (exact rounded formula) ----
    const int pxi = tx0 + (tid >> 4), pyi = ty0 + (tid & 15);
    const float px = (float)pxi, py = (float)pyi;
    const float p2 = px * px + py * py;          // exact (ints < 2^24)

    bool found = false;
    const int dcnt = dcnt_;
    for (int i = 0; i < dcnt; ++i) {
        const float4 gp = sgp[i];                // broadcast ds_read_b128
        const float cross = __fadd_rn(__fmul_rn(px, gp.x),
                                      __fmul_rn(py, gp.y));
        const float d2 = __fsub_rn(__fadd_rn(p2, gp.z),
                                   __fmul_rn(2.0f, cross));
        found |= (sqrtf(fmaxf(d2, 0.0f)) <= DIS_THR);
    }

    // ---- phase 3: scatter marks, division-free over deduped offsets ----
    const int total = scnt_ * K_PAD;
    for (int p = tid; p < total; p += 256) {
        const int s = p >> 6;
        const int k = p & (K_PAD - 1);
        const unsigned local = (unsigned)(sbase[s] + offl[k] - nmin);
        // in-tile iff flat-rel <= TILE_SPAN and column-rel < 16
        if (local <= (unsigned)TILE_SPAN && (local & 255u) < 16u)
            smark[((local >> 8) << 4) | (local & 15u)] = 1;
    }
    __syncthreads();

    // ---- phase 4: stores; priority scatter(+1) > covered(0) > negative(-1) ----
    const int n = (pxi << 8) | pyi;
    ((float2*)out)[b * HW + n] = make_float2(px, py);
    out[FLAG_OFF + b * HW + n] = smark[tid] ? 1.0f : (found ? 0.0f : -1.0f);
}

extern "C" void kernel_launch(void* const* d_in, const int* in_sizes, int n_in,
                              void* d_out, int out_size, void* d_ws, size_t ws_size,
                              hipStream_t stream) {
    // inputs: [0] images (unused), [1] gt_points, [2] gt_nums
    const float* gt_points = (const float*)d_in[1];
    const int*   gt_nums   = (const int*)d_in[2];
    float* out = (float*)d_out;

    // Ring offsets: host double trig (libm, matches numpy), half-even rint,
    // then dedup (marking is idempotent -> duplicates are redundant).
    OffsetsArg offs;
    {
        int raw[K_OFF];
        int k = 0;
        for (int i = 0; i < 5; ++i) {
            const int    nn = 8 * (i + 1);
            const double r  = 4.0 * (i + 1);
            for (int j = 0; j < nn; ++j) {
                const double ang = (double)j / (double)nn * 2.0 * M_PI;
                raw[k++] = (int)rint(r * sin(ang) * 256.0 +
                                     r * cos(ang) * 256.0);
            }
        }
        int u = 0;
        for (int a = 0; a < K_OFF; ++a) {
            bool seen = false;
            for (int bidx = 0; bidx < u; ++bidx)
                if (offs.v[bidx] == raw[a]) { seen = true; break; }
            if (!seen && u < K_PAD) offs.v[u++] = raw[a];
        }
        // ~61 unique expected; sentinels can never land in-tile
        for (; u < K_PAD; ++u) offs.v[u] = -0x40000000;
    }

    fused_kernel<<<dim3(16, 16, BS), 256, 0, stream>>>(gt_points, gt_nums, offs, out);
}

// Round 6
// 11.012 us; speedup vs baseline: 1.5660x; 1.1489x over previous
//
#include <hip/hip_runtime.h>
#include <math.h>

// Problem constants (fixed by setup_inputs / module constants)
#define BS   4
#define GMAX 500
#define HW   65536           // 256*256
#define K_OFF 120            // 8*(1+2+3+4+5) raw ring offsets
#define K_PAD 64             // deduped (~61 unique) + sentinels, power of 2
#define FLAG_OFF (BS * HW * 2)
#define OFF_MAX 7241         // max |round(256*(dx+dy))| over the rings
#define TILE_SPAN 3855       // 15*256 + 15 (flat span of a 16x16 tile)

// Exact replacement for sqrtf(max(d2,0)) <= 20 (both np and device sqrt are
// correctly-rounded f32): sqrt_rn(d2)<=20 <=> sqrt(d2) < 20+2^-20 (half-ulp)
// <=> d2 < 400 + 1.25*2^-15 <=> d2 <= 400 + 2^-15 (float spacing at 400).
// Negative d2: covered by both forms. Single compare, no sqrt sequence.
#define D2_THR 0x1.900002p+8f   // 400 + 2^-15

struct OffsetsArg { int v[K_PAD]; };

// ---------------------------------------------------------------------------
// One block = one 16x16 pixel tile of one image. 256 threads, 1 px/thread.
// grid (16,16,BS) = 1024 blocks -> 4 blocks/CU.
//   phase 1 (loop-free): 250 threads load 2 GT points each (float4);
//            wave-aggregated append (ballot + 1 atomic/wave) into LDS lists:
//            (a) disk: coord box overlap +-22 -> (gx,gy,g2,-) float4
//            (b) scatter: base flat index within +-OFF_MAX of tile span
//   phase 2: per-pixel disk test, single-compare d2 threshold (see D2_THR).
//   phase 3: scnt*64 grid-stride, division-free (s=p>>6, k=p&63), marks
//            into 256-entry LDS tile mask (idempotent constant writes).
//   phase 4: store pixels (float2) + flag = mark ? 1 : (covered ? 0 : -1).
// ---------------------------------------------------------------------------
__global__ __launch_bounds__(256) void fused_kernel(
    const float* __restrict__ gt_points,   // (BS, GMAX, 2)
    const int*   __restrict__ gt_nums,     // (BS,)
    OffsetsArg offs,                       // deduped ring offsets + sentinels
    float*       __restrict__ out)         // [BS*HW*2 pixels | BS*HW flag]
{
    const int b    = blockIdx.z;
    const int tx0  = blockIdx.x << 4;           // tile origin px
    const int ty0  = blockIdx.y << 4;           // tile origin py
    const int nmin = (tx0 << 8) + ty0;          // smallest flat index in tile

    __shared__ float4 sgp[GMAX];                // (gx, gy, g2, -) disk list
    __shared__ int    sbase[GMAX];              // scatter candidate bases
    __shared__ int    offl[K_PAD];
    __shared__ unsigned char smark[256];
    __shared__ int    dcnt_, scnt_;

    const int tid  = threadIdx.x;
    const int lane = tid & 63;
    if (tid == 0) { dcnt_ = 0; scnt_ = 0; }
    smark[tid] = 0;
    if (tid < K_PAD) offl[tid] = offs.v[tid];
    __syncthreads();                             // counters zeroed before atomics

    // ---- phase 1: candidate build, loop-free, wave-aggregated appends ----
    const int num = gt_nums[b];
    const float xlo = (float)(tx0 - 22), xhi = (float)(tx0 + 15 + 22);
    const float ylo = (float)(ty0 - 22), yhi = (float)(ty0 + 15 + 22);
    const int   blo = nmin - OFF_MAX,    bhi = nmin + TILE_SPAN + OFF_MAX;

    bool dc0 = false, dc1 = false, sc0 = false, sc1 = false;
    float gx0 = 0.f, gy0 = 0.f, gx1 = 0.f, gy1 = 0.f;
    int base0 = 0, base1 = 0;
    if (tid < 250) {                             // 250*2 = 500 = GMAX, no OOB
        const float4 q = ((const float4*)gt_points)[b * (GMAX / 2) + tid];
        gx0 = q.x; gy0 = q.y; gx1 = q.z; gy1 = q.w;
        const bool v0 = (2 * tid)     < num;
        const bool v1 = (2 * tid + 1) < num;
        dc0 = v0 & (gx0 >= xlo) & (gx0 <= xhi) & (gy0 >= ylo) & (gy0 <= yhi);
        dc1 = v1 & (gx1 >= xlo) & (gx1 <= xhi) & (gy1 >= ylo) & (gy1 <= yhi);
        // validated base formula: x*256, y*256 exact, one rounded add, rint
        base0 = (int)rintf(__fadd_rn(__fmul_rn(gx0, 256.0f),
                                     __fmul_rn(gy0, 256.0f)));
        base1 = (int)rintf(__fadd_rn(__fmul_rn(gx1, 256.0f),
                                     __fmul_rn(gy1, 256.0f)));
        sc0 = v0 & (base0 >= blo) & (base0 <= bhi);
        sc1 = v1 & (base1 >= blo) & (base1 <= bhi);
    }

#define APPEND_DISK(cond, gx, gy)                                            \
    {                                                                        \
        const unsigned long long m = __ballot(cond);                         \
        if (m) {                                                             \
            const int ldr = __builtin_ctzll(m);                              \
            int pos0 = 0;                                                    \
            if (lane == ldr) pos0 = atomicAdd(&dcnt_, __popcll(m));          \
            pos0 = __shfl(pos0, ldr);                                        \
            if (cond) {                                                      \
                const float g2 = __fadd_rn(__fmul_rn(gx, gx),                \
                                           __fmul_rn(gy, gy));               \
                sgp[pos0 + __popcll(m & ((1ull << lane) - 1))] =             \
                    make_float4(gx, gy, g2, 0.0f);                           \
            }                                                                \
        }                                                                    \
    }
#define APPEND_SCAT(cond, base)                                              \
    {                                                                        \
        const unsigned long long m = __ballot(cond);                         \
        if (m) {                                                             \
            const int ldr = __builtin_ctzll(m);                              \
            int pos0 = 0;                                                    \
            if (lane == ldr) pos0 = atomicAdd(&scnt_, __popcll(m));          \
            pos0 = __shfl(pos0, ldr);                                        \
            if (cond)                                                        \
                sbase[pos0 + __popcll(m & ((1ull << lane) - 1))] = base;     \
        }                                                                    \
    }

    APPEND_DISK(dc0, gx0, gy0)
    APPEND_DISK(dc1, gx1, gy1)
    APPEND_SCAT(sc0, base0)
    APPEND_SCAT(sc1, base1)
    __syncthreads();

    // ---- phase 2: per-pixel disk coverage (exact rounded formula) ----
    const int pxi = tx0 + (tid >> 4), pyi = ty0 + (tid & 15);
    const float px = (float)pxi, py = (float)pyi;
    const float p2 = px * px + py * py;          // exact (ints < 2^24)

    bool found = false;
    const int dcnt = dcnt_;
#pragma unroll 4
    for (int i = 0; i < dcnt; ++i) {
        const float4 gp = sgp[i];                // broadcast ds_read_b128
        const float cross = __fadd_rn(__fmul_rn(px, gp.x),
                                      __fmul_rn(py, gp.y));
        const float d2 = __fsub_rn(__fadd_rn(p2, gp.z),
                                   __fmul_rn(2.0f, cross));
        found |= (d2 <= D2_THR);
    }

    // ---- phase 3: scatter marks, division-free over deduped offsets ----
    const int total = scnt_ * K_PAD;
    for (int p = tid; p < total; p += 256) {
        const int s = p >> 6;
        const int k = p & (K_PAD - 1);
        const unsigned local = (unsigned)(sbase[s] + offl[k] - nmin);
        // in-tile iff flat-rel <= TILE_SPAN and column-rel < 16
        if (local <= (unsigned)TILE_SPAN && (local & 255u) < 16u)
            smark[((local >> 8) << 4) | (local & 15u)] = 1;
    }
    __syncthreads();

    // ---- phase 4: stores; priority scatter(+1) > covered(0) > negative(-1) ----
    const int n = (pxi << 8) | pyi;
    ((float2*)out)[b * HW + n] = make_float2(px, py);
    out[FLAG_OFF + b * HW + n] = smark[tid] ? 1.0f : (found ? 0.0f : -1.0f);
}

extern "C" void kernel_launch(void* const* d_in, const int* in_sizes, int n_in,
                              void* d_out, int out_size, void* d_ws, size_t ws_size,
                              hipStream_t stream) {
    // inputs: [0] images (unused), [1] gt_points, [2] gt_nums
    const float* gt_points = (const float*)d_in[1];
    const int*   gt_nums   = (const int*)d_in[2];
    float* out = (float*)d_out;

    // Ring offsets: host double trig (libm, matches numpy), half-even rint,
    // then dedup (marking is idempotent -> duplicates are redundant).
    OffsetsArg offs;
    {
        int raw[K_OFF];
        int k = 0;
        for (int i = 0; i < 5; ++i) {
            const int    nn = 8 * (i + 1);
            const double r  = 4.0 * (i + 1);
            for (int j = 0; j < nn; ++j) {
                const double ang = (double)j / (double)nn * 2.0 * M_PI;
                raw[k++] = (int)rint(r * sin(ang) * 256.0 +
                                     r * cos(ang) * 256.0);
            }
        }
        int u = 0;
        for (int a = 0; a < K_OFF; ++a) {
            bool seen = false;
            for (int bidx = 0; bidx < u; ++bidx)
                if (offs.v[bidx] == raw[a]) { seen = true; break; }
            if (!seen && u < K_PAD) offs.v[u++] = raw[a];
        }
        // ~61 unique expected; sentinels can never land in-tile
        for (; u < K_PAD; ++u) offs.v[u] = -0x40000000;
    }

    fused_kernel<<<dim3(16, 16, BS), 256, 0, stream>>>(gt_points, gt_nums, offs, out);
}